// Round 17
// baseline (4591.286 us; speedup 1.0000x reference)
//
#include <hip/hip_runtime.h>
#include <math.h>

#define T_SEQ 512
#define BATCH 256
#define HID   512
#define IN0   64
#define K1    1024           /* L1: 512 h0 + 512 h1 */
#define K0    576            /* L0: 64 x + 512 h0   */
#define NWG   256
#define NTHR  256
#define LDS_DYN 131072

typedef _Float16 f16x8 __attribute__((ext_vector_type(8)));
typedef float    f32x4 __attribute__((ext_vector_type(4)));

__device__ __forceinline__ float sigm(float x)   { return 1.0f / (1.0f + __expf(-x)); }
__device__ __forceinline__ float tanh_f(float x) { return 2.0f / (1.0f + __expf(-2.0f * x)) - 1.0f; }

__device__ __forceinline__ f32x4 mfma16(f16x8 a, f16x8 b, f32x4 c) {
  return __builtin_amdgcn_mfma_f32_16x16x32_f16(a, b, c, 0, 0, 0);
}

// ---- coherence-point (IF$) bypass ops: nothing is ever cached stale ----
__device__ __forceinline__ f16x8 load_f16x8_cc(const _Float16* p) {
  f16x8 r;
  asm volatile("global_load_dwordx4 %0, %1, off sc0 sc1"
               : "=v"(r) : "v"((const void*)p));
  return r;
}
__device__ __forceinline__ void store_short_wt(const _Float16* p, unsigned v) {
  asm volatile("global_store_short %0, %1, off sc0 sc1"
               :: "v"((const void*)p), "v"(v) : "memory");
}
__device__ __forceinline__ void store_dword_wt(const unsigned* p, unsigned v) {
  asm volatile("global_store_dword %0, %1, off sc0 sc1"
               :: "v"((const void*)p), "v"(v) : "memory");
}

// ---- monotonic signal helpers (agent scope, relaxed; release lines are WT) ----
__device__ __forceinline__ unsigned sig_add(unsigned* p) {
  return __hip_atomic_fetch_add(p, 1u, __ATOMIC_RELAXED, __HIP_MEMORY_SCOPE_AGENT);
}
__device__ __forceinline__ void sig_wait(const unsigned* p, unsigned tgt) {
  while ((int)(__hip_atomic_load(p, __ATOMIC_RELAXED, __HIP_MEMORY_SCOPE_AGENT) - tgt) < 0)
    __builtin_amdgcn_s_sleep(4);
}

// ---------- prep: W -> fp16, rows permuted r = hcol*4 + gate, k-concat ih|hh ----------
// out layout: [slice s=r>>4][kc=k>>3][row16=r&15][ke=k&7]  (16-B chunks contiguous)
__global__ void k_split_w(const float* __restrict__ Wih, const float* __restrict__ Whh,
                          const float* __restrict__ bih, const float* __restrict__ bhh,
                          _Float16* __restrict__ whi, float* __restrict__ bias, int Kin) {
  int K = Kin + HID;
  long idx = (long)blockIdx.x * 256 + threadIdx.x;
  long total = 2048L * K;
  if (idx < total) {
    int k = (int)(idx % K);
    int r = (int)(idx / K);
    int gate = r & 3, hcol = r >> 2;
    int row = gate * HID + hcol;
    float v = (k < Kin) ? Wih[(long)row * Kin + k] : Whh[(long)row * HID + (k - Kin)];
    long o = (long)(r >> 4) * 16 * K + (long)(k >> 3) * 128 + (r & 15) * 8 + (k & 7);
    whi[o] = (_Float16)v;
  }
  if (idx < 2048) {
    int r = (int)idx;
    int gate = r & 3, hcol = r >> 2;
    int row = gate * HID + hcol;
    bias[r] = bih[row] + bhh[row];
  }
}

// ---------- prep: x[B][T][I] -> fp16 [T][B][I] ----------
__global__ void k_split_x(const float* __restrict__ x, _Float16* __restrict__ x16) {
  int idx = blockIdx.x * 256 + threadIdx.x;   // dst index, [t][b][i]
  int i = idx & 63;
  int b = (idx >> 6) & 255;
  int t = idx >> 14;
  x16[idx] = (_Float16)x[((size_t)b * T_SEQ + t) * IN0 + i];
}

// ---------- persistent MFMA LSTM: producer/consumer signals, no global barrier ----------
// 256 wgs x 256 thr (4 waves, 1/SIMD). wg<128: layer1, rg=(wg&127)>>2, bg=wg&3;
// wg>=128: layer0 same on (wg-128). wg tile = 64 rows x 64 batch. Domain = bg
// (4 independent batch-group domains of 64 wgs: 32 L0 + 32 L1).
//
// Per-domain monotonic counters (each on its own 128-B line; release lines WT):
//   W0 / W0rel : L0 stores-done.  level after iter n = 32*(n+1)   (L0 active 0..511)
//   W1 / W1rel : L1 stores-done.  level after iter n = 32*n       (L1 active 1..512)
//   RD0/ RD0rel: L0 reads-done.   level after iter n = 32*(n+1)
//   RD1/ RD1rel: L1 reads-done.   level after iter n = 32*n
// Dependencies at iter n (reads from parity (n+1)&1, writes parity n&1):
//   L0 loads (h0 only)  <- W0rel >= 32n
//   L1 bufA (h0 half)   <- W0rel >= 32n ;  L1 bufB (h1 half) <- W1rel >= 32(n-1)
//   any store           <- RD0rel >= 32n && RD1rel >= 32(n-1)   (iter n-1 readers done)
// Soundness: per-type counters — a wg's arrival at level L requires ALL peer
// stores at L-1, which require those wgs' own prior RD arrival (program order),
// so counter==level <=> every wg of that type reached it. (Mixed-type counters
// would be ambiguous; hence the 4-way split.)
// Data release: WT stores drained (vmcnt(0)) before signaling. Data acquire:
// all cross-wg data read via sc0sc1 bypass -> no stale cache -> no inv needed.
__global__ __launch_bounds__(NTHR, 1) void k_lstm(
    const _Float16* __restrict__ x16,
    const _Float16* __restrict__ w0, const float* __restrict__ bias0,
    const _Float16* __restrict__ w1, const float* __restrict__ bias1,
    _Float16* __restrict__ in1,
    const float* __restrict__ fcw, const float* __restrict__ fcb,
    float* __restrict__ out, unsigned* __restrict__ bar)
{
  extern __shared__ __align__(16) _Float16 ldsA[];   // 64 rows x KW fp16

  const int tid  = threadIdx.x;
  const int lane = tid & 63;
  const int wv   = __builtin_amdgcn_readfirstlane(tid >> 6);   // 0..3
  const int wg   = blockIdx.x;
  const int layer1 = (wg < 128) ? 1 : 0;
  const int lw   = wg & 127;
  const int rg   = lw >> 2;            // 0..31 row-group (64 rows)
  const int bg   = lw & 3;             // 0..3 batch-group (64 batch) == domain
  const unsigned dom = (unsigned)bg;
  const int bbase = bg * 64 + wv * 16;
  const int lr = lane & 15;            // A-row16 / B-batch / D-col offset
  const int lg = lane >> 4;            // k-subgroup (A/B), row-subgroup (D)
  const int KW = layer1 ? K1 : K0;

  // per-domain signal lines
  unsigned* RD0c = bar + 0   + dom * 32;
  unsigned* RD0r = bar + 128 + dom * 32;
  unsigned* RD1c = bar + 256 + dom * 32;
  unsigned* RD1r = bar + 384 + dom * 32;
  unsigned* W0c  = bar + 512 + dom * 32;
  unsigned* W0r  = bar + 640 + dom * 32;
  unsigned* W1c  = bar + 768 + dom * 32;
  unsigned* W1r  = bar + 896 + dom * 32;

  // ---- one-time: load this wg's 64-row weight slice into LDS ----
  {
    const f16x8* gw = reinterpret_cast<const f16x8*>((layer1 ? w1 : w0) + (size_t)rg * 64 * KW);
    f16x8* lw16 = reinterpret_cast<f16x8*>(ldsA);
    const int nch = 8 * KW;            // 64*KW/8 chunks of 16 B
    for (int ch = tid; ch < nch; ch += NTHR) lw16[ch] = gw[ch];
  }
  __syncthreads();

  // lane's hidden columns (4 row-slices) and biases
  const float* bsrc = layer1 ? bias1 : bias0;
  float4 b4[4];
  int hcv[4];
  #pragma unroll
  for (int sl = 0; sl < 4; ++sl) {
    hcv[sl] = rg * 16 + sl * 4 + lg;
    b4[sl] = *reinterpret_cast<const float4*>(bsrc + hcv[sl] * 4);
  }
  const f16x8* A = reinterpret_cast<const f16x8*>(ldsA);   // slice sl at sl*2*KW (f16x8 units)

  float c[4] = {0.f, 0.f, 0.f, 0.f};

  #pragma unroll 1
  for (int n = 0; n <= T_SEQ; ++n) {
    const int pr = (n + 1) & 1;   // read parity
    const int pw = n & 1;         // write parity
    const bool active = layer1 ? (n >= 1) : (n < T_SEQ);
    if (active) {
      f32x4 acc[4];
      #pragma unroll
      for (int sl = 0; sl < 4; ++sl) {
        acc[sl][0]=b4[sl].x; acc[sl][1]=b4[sl].y; acc[sl][2]=b4[sl].z; acc[sl][3]=b4[sl].w;
      }

      const _Float16* Bp = in1 + ((size_t)pr * BATCH + bbase) * K1 + (size_t)lr * K1 + lg * 8;

      if (layer1) {
        // --- wait h0 producers (L0 iter n-1) ; issue bufA ---
        if (tid == 0) sig_wait(W0r, 32u * (unsigned)n);
        __syncthreads();
        f16x8 bufA[16], bufB[16];
        #pragma unroll
        for (int kk = 0; kk < 16; ++kk)
          bufA[kk] = load_f16x8_cc(Bp + (size_t)kk * 32);
        // --- wait h1 producers (L1 iter n-1) while bufA is in flight; issue bufB ---
        if (tid == 0) sig_wait(W1r, 32u * (unsigned)(n - 1));
        __syncthreads();
        #pragma unroll
        for (int kk = 0; kk < 16; ++kk)
          bufB[kk] = load_f16x8_cc(Bp + (size_t)(16 + kk) * 32);
        asm volatile("s_waitcnt vmcnt(16)" ::: "memory");   // bufA complete
        __builtin_amdgcn_sched_barrier(0);
        #pragma unroll
        for (int kk = 0; kk < 16; ++kk) {
          const int ac = (kk * 4 + lg) * 16 + lr;
          #pragma unroll
          for (int sl = 0; sl < 4; ++sl)
            acc[sl] = mfma16(A[(size_t)sl * 2 * K1 + ac], bufA[kk], acc[sl]);
        }
        asm volatile("s_waitcnt vmcnt(0)" ::: "memory");    // bufB complete
        __builtin_amdgcn_sched_barrier(0);
        __syncthreads();                                    // all waves' reads done
        if (tid == 0) {                                     // reads-done arrival
          unsigned a = sig_add(RD1c);
          if (a == 32u * (unsigned)n - 1u) store_dword_wt(RD1r, 32u * (unsigned)n);
        }
        #pragma unroll
        for (int kk = 0; kk < 16; ++kk) {
          const int ac = ((16 + kk) * 4 + lg) * 16 + lr;
          #pragma unroll
          for (int sl = 0; sl < 4; ++sl)
            acc[sl] = mfma16(A[(size_t)sl * 2 * K1 + ac], bufB[kk], acc[sl]);
        }
      } else {
        // --- x loads need no wait; then wait h0 producers; issue bufA ---
        const _Float16* Xp = x16 + ((size_t)n * BATCH + bbase) * IN0 + (size_t)lr * IN0 + lg * 8;
        f16x8 xb0 = load_f16x8_cc(Xp);
        f16x8 xb1 = load_f16x8_cc(Xp + 32);
        if (tid == 0 && n > 0) sig_wait(W0r, 32u * (unsigned)n);
        __syncthreads();
        f16x8 bufA[16];
        #pragma unroll
        for (int kk = 0; kk < 16; ++kk)
          bufA[kk] = load_f16x8_cc(Bp + (size_t)kk * 32);
        asm volatile("s_waitcnt vmcnt(16)" ::: "memory");   // xb0, xb1 complete
        __builtin_amdgcn_sched_barrier(0);
        #pragma unroll
        for (int sl = 0; sl < 4; ++sl)
          acc[sl] = mfma16(A[(size_t)sl * 2 * K0 + (lg * 16 + lr)], xb0, acc[sl]);
        #pragma unroll
        for (int sl = 0; sl < 4; ++sl)
          acc[sl] = mfma16(A[(size_t)sl * 2 * K0 + ((4 + lg) * 16 + lr)], xb1, acc[sl]);
        asm volatile("s_waitcnt vmcnt(0)" ::: "memory");    // bufA complete
        __builtin_amdgcn_sched_barrier(0);
        __syncthreads();                                    // all waves' reads done
        if (tid == 0) {                                     // reads-done arrival
          unsigned a = sig_add(RD0c);
          if (a == 32u * (unsigned)(n + 1) - 1u) store_dword_wt(RD0r, 32u * (unsigned)(n + 1));
        }
        #pragma unroll
        for (int kk = 0; kk < 16; ++kk) {
          const int ac = (8 + kk * 4 + lg) * 16 + lr;   // weight k-offset 64
          #pragma unroll
          for (int sl = 0; sl < 4; ++sl)
            acc[sl] = mfma16(A[(size_t)sl * 2 * K0 + ac], bufA[kk], acc[sl]);
        }
      }

      // ---- anti-dependency: iter n-1 readers of parity pw must be done ----
      if (tid == 0 && n >= 1) {
        sig_wait(RD0r, 32u * (unsigned)n);          // cumRD0(n-1)
        sig_wait(RD1r, 32u * (unsigned)(n - 1));    // cumRD1(n-1)
      }
      __syncthreads();

      // ---- lane-local cell update; write-through fp16 h stores ----
      const int b = bbase + lr;
      #pragma unroll
      for (int sl = 0; sl < 4; ++sl) {
        float i_ = sigm(acc[sl][0]);
        float f_ = sigm(acc[sl][1]);
        float g_ = tanh_f(acc[sl][2]);
        float o_ = sigm(acc[sl][3]);
        c[sl] = fmaf(f_, c[sl], i_ * g_);
        float hv = o_ * tanh_f(c[sl]);
        _Float16 h16 = (_Float16)hv;
        const int col = (layer1 ? 512 : 0) + hcv[sl];
        const size_t idx = ((size_t)pw * BATCH + b) * K1 + col;
        store_short_wt(in1 + idx, (unsigned)__builtin_bit_cast(unsigned short, h16));
      }
      asm volatile("s_waitcnt vmcnt(0)" ::: "memory");  // stores at coherence point
      __syncthreads();                                  // all waves drained
      if (tid == 0) {                                   // stores-done arrival
        if (layer1) {
          unsigned a = sig_add(W1c);
          if (a == 32u * (unsigned)n - 1u) store_dword_wt(W1r, 32u * (unsigned)n);
        } else {
          unsigned a = sig_add(W0c);
          if (a == 32u * (unsigned)(n + 1) - 1u) store_dword_wt(W0r, 32u * (unsigned)(n + 1));
        }
      }
    }
  }

  // ---- final FC on h1[511] (parity 0), cols 512..1023 — wait all domains' L1 ----
  if (wg == 0) {
    if (tid == 0) {
      #pragma unroll
      for (int d = 0; d < 4; ++d)
        sig_wait(bar + 896 + d * 32, 32u * (unsigned)T_SEQ);
      __builtin_amdgcn_fence(__ATOMIC_ACQUIRE, "agent");   // one-time acquire
    }
    __syncthreads();
    if (tid < BATCH) {
      const _Float16* r = in1 + (size_t)tid * K1 + 512;
      float acc = 0.f;
      #pragma unroll 8
      for (int k = 0; k < HID; ++k)
        acc = fmaf((float)r[k], fcw[k], acc);
      out[tid] = acc + fcb[0];
    }
  }
}

// ---------- host ----------
extern "C" void kernel_launch(void* const* d_in, const int* in_sizes, int n_in,
                              void* d_out, int out_size, void* d_ws, size_t ws_size,
                              hipStream_t stream) {
  const float* x    = (const float*)d_in[0];
  const float* Wih0 = (const float*)d_in[1];
  const float* Whh0 = (const float*)d_in[2];
  const float* bih0 = (const float*)d_in[3];
  const float* bhh0 = (const float*)d_in[4];
  const float* Wih1 = (const float*)d_in[5];
  const float* Whh1 = (const float*)d_in[6];
  const float* bih1 = (const float*)d_in[7];
  const float* bhh1 = (const float*)d_in[8];
  const float* fcw  = (const float*)d_in[9];
  const float* fcb  = (const float*)d_in[10];

  char* ws = (char*)d_ws;
  size_t off = 0;
  auto alloc = [&](size_t bytes) -> char* {
    char* pp = ws + off;
    off = (off + bytes + 1023) & ~(size_t)1023;
    return pp;
  };
  unsigned*  bar  = (unsigned*)alloc(4096);
  _Float16* x16  = (_Float16*)alloc((size_t)T_SEQ * BATCH * IN0 * 2);   // 16.8 MB
  _Float16* w0   = (_Float16*)alloc((size_t)2048 * K0 * 2);             // 2.36 MB
  _Float16* w1   = (_Float16*)alloc((size_t)2048 * K1 * 2);             // 4.2 MB
  float*    bias0 = (float*)alloc(2048 * 4);
  float*    bias1 = (float*)alloc(2048 * 4);
  _Float16* in1  = (_Float16*)alloc((size_t)2 * BATCH * K1 * 2);        // 1 MB

  (void)hipFuncSetAttribute(reinterpret_cast<const void*>(k_lstm),
                            hipFuncAttributeMaxDynamicSharedMemorySize, LDS_DYN);

  (void)hipMemsetAsync(bar, 0, 4096, stream);
  (void)hipMemsetAsync(in1, 0, (size_t)2 * BATCH * K1 * 2, stream);
  k_split_x<<<(T_SEQ * BATCH * IN0) / 256, 256, 0, stream>>>(x, x16);
  k_split_w<<<(int)((2048L * K0 + 255) / 256), 256, 0, stream>>>(Wih0, Whh0, bih0, bhh0, w0, bias0, IN0);
  k_split_w<<<(int)((2048L * K1 + 255) / 256), 256, 0, stream>>>(Wih1, Whh1, bih1, bhh1, w1, bias1, HID);
  k_lstm<<<NWG, NTHR, LDS_DYN, stream>>>(x16, w0, bias0, w1, bias1,
                                         in1, fcw, fcb, (float*)d_out, bar);
}

// Round 18
// 4326.502 us; speedup vs baseline: 1.0612x; 1.0612x over previous
//
#include <hip/hip_runtime.h>
#include <math.h>

#define T_SEQ 512
#define BATCH 256
#define HID   512
#define IN0   64
#define K1    1024           /* L1: 512 h0 + 512 h1 */
#define K0    576            /* L0: 64 x + 512 h0   */
#define NWG   256
#define NTHR  256
#define LDS_DYN 131072

typedef _Float16 f16x8 __attribute__((ext_vector_type(8)));
typedef float    f32x4 __attribute__((ext_vector_type(4)));

__device__ __forceinline__ float sigm(float x)   { return 1.0f / (1.0f + __expf(-x)); }
__device__ __forceinline__ float tanh_f(float x) { return 2.0f / (1.0f + __expf(-2.0f * x)) - 1.0f; }

__device__ __forceinline__ f32x4 mfma16(f16x8 a, f16x8 b, f32x4 c) {
  return __builtin_amdgcn_mfma_f32_16x16x32_f16(a, b, c, 0, 0, 0);
}

// ---- coherence-point (IF$) bypass ops: nothing is ever cached stale ----
__device__ __forceinline__ f16x8 load_f16x8_cc(const _Float16* p) {
  f16x8 r;
  asm volatile("global_load_dwordx4 %0, %1, off sc0 sc1"
               : "=v"(r) : "v"((const void*)p));
  return r;
}
__device__ __forceinline__ void store_short_wt(const _Float16* p, unsigned v) {
  asm volatile("global_store_short %0, %1, off sc0 sc1"
               :: "v"((const void*)p), "v"(v) : "memory");
}
__device__ __forceinline__ void store_dword_wt(const unsigned* p, unsigned v) {
  asm volatile("global_store_dword %0, %1, off sc0 sc1"
               :: "v"((const void*)p), "v"(v) : "memory");
}

// ---------- prep: W -> fp16, rows permuted r = hcol*4 + gate, k-concat ih|hh ----------
// out layout: [slice s=r>>4][kc=k>>3][row16=r&15][ke=k&7]  (16-B chunks contiguous)
__global__ void k_split_w(const float* __restrict__ Wih, const float* __restrict__ Whh,
                          const float* __restrict__ bih, const float* __restrict__ bhh,
                          _Float16* __restrict__ whi, float* __restrict__ bias, int Kin) {
  int K = Kin + HID;
  long idx = (long)blockIdx.x * 256 + threadIdx.x;
  long total = 2048L * K;
  if (idx < total) {
    int k = (int)(idx % K);
    int r = (int)(idx / K);
    int gate = r & 3, hcol = r >> 2;
    int row = gate * HID + hcol;
    float v = (k < Kin) ? Wih[(long)row * Kin + k] : Whh[(long)row * HID + (k - Kin)];
    long o = (long)(r >> 4) * 16 * K + (long)(k >> 3) * 128 + (r & 15) * 8 + (k & 7);
    whi[o] = (_Float16)v;
  }
  if (idx < 2048) {
    int r = (int)idx;
    int gate = r & 3, hcol = r >> 2;
    int row = gate * HID + hcol;
    bias[r] = bih[row] + bhh[row];
  }
}

// ---------- prep: x[B][T][I] -> fp16 [T][B][I] ----------
__global__ void k_split_x(const float* __restrict__ x, _Float16* __restrict__ x16) {
  int idx = blockIdx.x * 256 + threadIdx.x;   // dst index, [t][b][i]
  int i = idx & 63;
  int b = (idx >> 6) & 255;
  int t = idx >> 14;
  x16[idx] = (_Float16)x[((size_t)b * T_SEQ + t) * IN0 + i];
}

// ---------- per-domain barrier (4 independent batch-group domains), NO fence ----------
// Domain d = wg&3 owns batch rows d*64..d*64+63. All recurrent dataflow
// (h0 self-recurrence, h0->L1, h1 self-recurrence) is batch-diagonal, so a wg
// only depends on the 64 wgs (32 L0 + 32 L1) of its own domain.
// bar[d*32]       : domain arrival counter (monotonic; epoch e done at 64*e)
// bar[256+d*32]   : domain release line (WT store of epoch; polled)
// Data release: callers drain WT stores (s_waitcnt vmcnt(0)) before arriving.
// Data acquire: all cross-wg data (in1) is read via sc0sc1 bypass loads ->
// no stale copy can exist in any L1/L2 -> no per-iteration buffer_inv needed.
__device__ __forceinline__ void grid_barrier(unsigned* bar, unsigned epoch, unsigned dom) {
  __syncthreads();
  if (threadIdx.x == 0) {
    unsigned a = __hip_atomic_fetch_add(&bar[dom * 32], 1u,
                                        __ATOMIC_RELAXED, __HIP_MEMORY_SCOPE_AGENT);
    if (a == epoch * 64u - 1u)     // last of this domain's 64 arrivals this epoch
      store_dword_wt(&bar[256 + dom * 32], epoch);
    while ((int)(__hip_atomic_load(&bar[256 + dom * 32],
                                   __ATOMIC_RELAXED, __HIP_MEMORY_SCOPE_AGENT) - epoch) < 0)
      __builtin_amdgcn_s_sleep(4);
  }
  __syncthreads();
}

// ---------- persistent MFMA LSTM (fp16, 64-row tiles, fence-free, domain sync) ----------
// 256 wgs x 256 thr (4 waves, 1/SIMD). wg<128: layer1, rg=(wg&127)>>2, bg=wg&3;
// wg>=128: layer0 same on (wg-128). wg tile = 64 rows x 64 batch. Domain = bg.
// Wave wv: batch block bg*64+wv*16 (EXCLUSIVE 16-col B tile -> B issued once per
// byte per CU); computes all 4 row-slices: acc[4], c[4].
// fp16 weights for the wg's 64 rows in 128 KB dynamic LDS, loaded ONCE.
// Inner-loop h/x loads are sc0sc1 bypass (asm) with counted vmcnt waits
// (vmcnt(16) -> first half, vmcnt(0) -> rest) + sched_barrier(0) after each
// wait (asm loads are invisible to compiler vmcnt tracking — rule #18).
// D layout: col=lane&15 (batch), row=(lane>>4)*4+reg. Rows permuted hcol*4+gate =>
// lane's 4 acc regs = i,f,g,o of one (hcol,batch): cell update lane-local, c in regs.
// Activations in1 (fp16) [2][256][1024]: cols 0..511 = h0, 512..1023 = h1, k-major.
__global__ __launch_bounds__(NTHR, 1) void k_lstm(
    const _Float16* __restrict__ x16,
    const _Float16* __restrict__ w0, const float* __restrict__ bias0,
    const _Float16* __restrict__ w1, const float* __restrict__ bias1,
    _Float16* __restrict__ in1,
    const float* __restrict__ fcw, const float* __restrict__ fcb,
    float* __restrict__ out, unsigned* __restrict__ bar)
{
  extern __shared__ __align__(16) _Float16 ldsA[];   // 64 rows x KW fp16

  const int tid  = threadIdx.x;
  const int lane = tid & 63;
  const int wv   = __builtin_amdgcn_readfirstlane(tid >> 6);   // 0..3
  const int wg   = blockIdx.x;
  const int layer1 = (wg < 128) ? 1 : 0;
  const int lw   = wg & 127;
  const int rg   = lw >> 2;            // 0..31 row-group (64 rows)
  const int bg   = lw & 3;             // 0..3 batch-group (64 batch) == sync domain
  const unsigned dom = (unsigned)bg;
  const int bbase = bg * 64 + wv * 16;
  const int lr = lane & 15;            // A-row16 / B-batch / D-col offset
  const int lg = lane >> 4;            // k-subgroup (A/B), row-subgroup (D)
  const int KW = layer1 ? K1 : K0;

  // ---- one-time: load this wg's 64-row weight slice into LDS ----
  {
    const f16x8* gw = reinterpret_cast<const f16x8*>((layer1 ? w1 : w0) + (size_t)rg * 64 * KW);
    f16x8* lw16 = reinterpret_cast<f16x8*>(ldsA);
    const int nch = 8 * KW;            // 64*KW/8 chunks of 16 B
    for (int ch = tid; ch < nch; ch += NTHR) lw16[ch] = gw[ch];
  }
  __syncthreads();

  // lane's hidden columns (4 row-slices) and biases
  const float* bsrc = layer1 ? bias1 : bias0;
  float4 b4[4];
  int hcv[4];
  #pragma unroll
  for (int sl = 0; sl < 4; ++sl) {
    hcv[sl] = rg * 16 + sl * 4 + lg;
    b4[sl] = *reinterpret_cast<const float4*>(bsrc + hcv[sl] * 4);
  }
  const f16x8* A = reinterpret_cast<const f16x8*>(ldsA);   // slice sl at sl*2*KW (f16x8 units)

  float c[4] = {0.f, 0.f, 0.f, 0.f};

  #pragma unroll 1
  for (int n = 0; n <= T_SEQ; ++n) {
    const int pr = (n + 1) & 1;   // read parity
    const int pw = n & 1;         // write parity
    const bool active = layer1 ? (n >= 1) : (n < T_SEQ);
    if (active) {
      f32x4 acc[4];
      #pragma unroll
      for (int sl = 0; sl < 4; ++sl) {
        acc[sl][0]=b4[sl].x; acc[sl][1]=b4[sl].y; acc[sl][2]=b4[sl].z; acc[sl][3]=b4[sl].w;
      }

      const _Float16* Bp = in1 + ((size_t)pr * BATCH + bbase) * K1 + (size_t)lr * K1 + lg * 8;

      if (layer1) {
        // 32 k-chunks, all loads issued as sc-bypass; counted waits split halves
        f16x8 bufA[16], bufB[16];
        #pragma unroll
        for (int kk = 0; kk < 16; ++kk)
          bufA[kk] = load_f16x8_cc(Bp + (size_t)kk * 32);
        #pragma unroll
        for (int kk = 0; kk < 16; ++kk)
          bufB[kk] = load_f16x8_cc(Bp + (size_t)(16 + kk) * 32);
        asm volatile("s_waitcnt vmcnt(16)" ::: "memory");   // bufA complete
        __builtin_amdgcn_sched_barrier(0);
        #pragma unroll
        for (int kk = 0; kk < 16; ++kk) {
          const int ac = (kk * 4 + lg) * 16 + lr;
          #pragma unroll
          for (int sl = 0; sl < 4; ++sl)
            acc[sl] = mfma16(A[(size_t)sl * 2 * K1 + ac], bufA[kk], acc[sl]);
        }
        asm volatile("s_waitcnt vmcnt(0)" ::: "memory");    // bufB complete
        __builtin_amdgcn_sched_barrier(0);
        #pragma unroll
        for (int kk = 0; kk < 16; ++kk) {
          const int ac = ((16 + kk) * 4 + lg) * 16 + lr;
          #pragma unroll
          for (int sl = 0; sl < 4; ++sl)
            acc[sl] = mfma16(A[(size_t)sl * 2 * K1 + ac], bufB[kk], acc[sl]);
        }
      } else {
        // x part (2 chunks) + h0 part (16 chunks); x loads are oldest -> return first
        const _Float16* Xp = x16 + ((size_t)n * BATCH + bbase) * IN0 + (size_t)lr * IN0 + lg * 8;
        f16x8 xb0 = load_f16x8_cc(Xp);
        f16x8 xb1 = load_f16x8_cc(Xp + 32);
        f16x8 bufA[16];
        #pragma unroll
        for (int kk = 0; kk < 16; ++kk)
          bufA[kk] = load_f16x8_cc(Bp + (size_t)kk * 32);
        asm volatile("s_waitcnt vmcnt(16)" ::: "memory");   // xb0, xb1 complete
        __builtin_amdgcn_sched_barrier(0);
        #pragma unroll
        for (int sl = 0; sl < 4; ++sl)
          acc[sl] = mfma16(A[(size_t)sl * 2 * K0 + (lg * 16 + lr)], xb0, acc[sl]);
        #pragma unroll
        for (int sl = 0; sl < 4; ++sl)
          acc[sl] = mfma16(A[(size_t)sl * 2 * K0 + ((4 + lg) * 16 + lr)], xb1, acc[sl]);
        asm volatile("s_waitcnt vmcnt(0)" ::: "memory");    // bufA complete
        __builtin_amdgcn_sched_barrier(0);
        #pragma unroll
        for (int kk = 0; kk < 16; ++kk) {
          const int ac = (8 + kk * 4 + lg) * 16 + lr;   // weight k-offset 64
          #pragma unroll
          for (int sl = 0; sl < 4; ++sl)
            acc[sl] = mfma16(A[(size_t)sl * 2 * K0 + ac], bufA[kk], acc[sl]);
        }
      }

      // ---- lane-local cell update; write-through fp16 h stores ----
      const int b = bbase + lr;
      #pragma unroll
      for (int sl = 0; sl < 4; ++sl) {
        float i_ = sigm(acc[sl][0]);
        float f_ = sigm(acc[sl][1]);
        float g_ = tanh_f(acc[sl][2]);
        float o_ = sigm(acc[sl][3]);
        c[sl] = fmaf(f_, c[sl], i_ * g_);
        float hv = o_ * tanh_f(c[sl]);
        _Float16 h16 = (_Float16)hv;
        const int col = (layer1 ? 512 : 0) + hcv[sl];
        const size_t idx = ((size_t)pw * BATCH + b) * K1 + col;
        store_short_wt(in1 + idx, (unsigned)__builtin_bit_cast(unsigned short, h16));
      }
      asm volatile("s_waitcnt vmcnt(0)" ::: "memory");  // release: stores at coherence point
    }
    grid_barrier(bar, (unsigned)(n + 1), dom);
  }

  // ---- final FC on h1[511] (parity 0), cols 512..1023 — wait on ALL domains ----
  if (wg == 0) {
    if (tid == 0) {
      #pragma unroll
      for (int d = 0; d < 4; ++d)
        while ((int)(__hip_atomic_load(&bar[256 + d * 32],
                                       __ATOMIC_RELAXED, __HIP_MEMORY_SCOPE_AGENT)
                     - (unsigned)(T_SEQ + 1)) < 0)
          __builtin_amdgcn_s_sleep(4);
      __builtin_amdgcn_fence(__ATOMIC_ACQUIRE, "agent");   // one-time acquire
    }
    __syncthreads();
    if (tid < BATCH) {
      const _Float16* r = in1 + (size_t)tid * K1 + 512;
      float acc = 0.f;
      #pragma unroll 8
      for (int k = 0; k < HID; ++k)
        acc = fmaf((float)r[k], fcw[k], acc);
      out[tid] = acc + fcb[0];
    }
  }
}

// ---------- host ----------
extern "C" void kernel_launch(void* const* d_in, const int* in_sizes, int n_in,
                              void* d_out, int out_size, void* d_ws, size_t ws_size,
                              hipStream_t stream) {
  const float* x    = (const float*)d_in[0];
  const float* Wih0 = (const float*)d_in[1];
  const float* Whh0 = (const float*)d_in[2];
  const float* bih0 = (const float*)d_in[3];
  const float* bhh0 = (const float*)d_in[4];
  const float* Wih1 = (const float*)d_in[5];
  const float* Whh1 = (const float*)d_in[6];
  const float* bih1 = (const float*)d_in[7];
  const float* bhh1 = (const float*)d_in[8];
  const float* fcw  = (const float*)d_in[9];
  const float* fcb  = (const float*)d_in[10];

  char* ws = (char*)d_ws;
  size_t off = 0;
  auto alloc = [&](size_t bytes) -> char* {
    char* pp = ws + off;
    off = (off + bytes + 1023) & ~(size_t)1023;
    return pp;
  };
  unsigned*  bar  = (unsigned*)alloc(4096);
  _Float16* x16  = (_Float16*)alloc((size_t)T_SEQ * BATCH * IN0 * 2);   // 16.8 MB
  _Float16* w0   = (_Float16*)alloc((size_t)2048 * K0 * 2);             // 2.36 MB
  _Float16* w1   = (_Float16*)alloc((size_t)2048 * K1 * 2);             // 4.2 MB
  float*    bias0 = (float*)alloc(2048 * 4);
  float*    bias1 = (float*)alloc(2048 * 4);
  _Float16* in1  = (_Float16*)alloc((size_t)2 * BATCH * K1 * 2);        // 1 MB

  (void)hipFuncSetAttribute(reinterpret_cast<const void*>(k_lstm),
                            hipFuncAttributeMaxDynamicSharedMemorySize, LDS_DYN);

  (void)hipMemsetAsync(bar, 0, 4096, stream);
  (void)hipMemsetAsync(in1, 0, (size_t)2 * BATCH * K1 * 2, stream);
  k_split_x<<<(T_SEQ * BATCH * IN0) / 256, 256, 0, stream>>>(x, x16);
  k_split_w<<<(int)((2048L * K0 + 255) / 256), 256, 0, stream>>>(Wih0, Whh0, bih0, bhh0, w0, bias0, IN0);
  k_split_w<<<(int)((2048L * K1 + 255) / 256), 256, 0, stream>>>(Wih1, Whh1, bih1, bhh1, w1, bias1, HID);
  k_lstm<<<NWG, NTHR, LDS_DYN, stream>>>(x16, w0, bias0, w1, bias1,
                                         in1, fcw, fcb, (float*)d_out, bar);
}